// Round 2
// baseline (849.402 us; speedup 1.0000x reference)
//
#include <hip/hip_runtime.h>
#include <hip/hip_bf16.h>
#include <stdint.h>

#define N_NODES 16384
#define IN_SIZE 4096
#define EMB 500
#define EMBP 512
#define NEDGE 524288

typedef __attribute__((ext_vector_type(8))) short bf16x8_t;
typedef __attribute__((ext_vector_type(4))) float f32x4_t;

__device__ __forceinline__ unsigned short f2bf(float f) {
    union { float f; unsigned u; } v; v.f = f;
    unsigned r = v.u + 0x7FFFu + ((v.u >> 16) & 1u);
    return (unsigned short)(r >> 16);
}
__device__ __forceinline__ float bf2f(unsigned short h) {
    union { float f; unsigned u; } v; v.u = ((unsigned)h) << 16;
    return v.f;
}

// packed fp32x2 -> bf16x2 (RNE); lowers to v_cvt_pk_bf16_f32 on gfx950
__device__ __forceinline__ unsigned pkbf2(float a, float b) {
    union { __hip_bfloat162 h; unsigned u; } c;
    c.h = __float22bfloat162_rn(float2{a, b});
    return c.u;
}
// 8 consecutive fp32 in LDS -> bf16x8 MFMA fragment
__device__ __forceinline__ bf16x8_t cvt8(const float* p) {
    f32x4_t lo = *(const f32x4_t*)p;
    f32x4_t hi = *(const f32x4_t*)(p + 4);
    union { bf16x8_t v; unsigned u[4]; } r;
    r.u[0] = pkbf2(lo[0], lo[1]);
    r.u[1] = pkbf2(lo[2], lo[3]);
    r.u[2] = pkbf2(hi[0], hi[1]);
    r.u[3] = pkbf2(hi[2], hi[3]);
    return r.v;
}

// async global->LDS, 16B per lane. LDS dest is wave-uniform base + lane*16.
__device__ __forceinline__ void gload_lds16(const void* g, void* l) {
    __builtin_amdgcn_global_load_lds(
        (__attribute__((address_space(1))) void*)(g),
        (__attribute__((address_space(3))) void*)(l),
        16, 0, 0);
}

__global__ void zero_i32(int* p, int n) {
    int i = blockIdx.x * 256 + threadIdx.x;
    if (i < n) p[i] = 0;
}

// edge_index delivered by harness as int32 [2, E]: row = ei[e], col = ei[E + e]
__global__ void hist_k(const int* __restrict__ ei, int* __restrict__ deg, int* __restrict__ coldeg) {
    int e = blockIdx.x * 256 + threadIdx.x;
    int r = ei[e];
    int c = ei[NEDGE + e];
    atomicAdd(&deg[r], 1);
    atomicAdd(&coldeg[c], 1);
}

__global__ void dinv_k(const int* __restrict__ deg, float* __restrict__ dinv) {
    int i = blockIdx.x * 256 + threadIdx.x;
    int d = deg[i];
    dinv[i] = d > 0 ? rsqrtf((float)d) : 0.f;
}

// exclusive scan of coldeg[16384] -> colptr[16385]; cursor = copy of colptr[0:16384]
__global__ void scan_k(const int* __restrict__ coldeg, int* __restrict__ colptr, int* __restrict__ cursor) {
    __shared__ int part[256];
    int t = threadIdx.x;
    int base = t * 64;
    int s = 0;
    for (int i = 0; i < 64; ++i) s += coldeg[base + i];
    part[t] = s;
    __syncthreads();
    for (int off = 1; off < 256; off <<= 1) {
        int v = part[t];
        int add = (t >= off) ? part[t - off] : 0;
        __syncthreads();
        part[t] = v + add;
        __syncthreads();
    }
    int ex = (t > 0) ? part[t - 1] : 0;
    for (int i = 0; i < 64; ++i) {
        colptr[base + i] = ex;
        cursor[base + i] = ex;
        ex += coldeg[base + i];
    }
    if (t == 255) colptr[N_NODES] = ex;
}

__global__ void fill_k(const int* __restrict__ ei, const float* __restrict__ dinv,
                       int* __restrict__ cursor, int* __restrict__ csr_src, float* __restrict__ csr_nrm) {
    int e = blockIdx.x * 256 + threadIdx.x;
    int r = ei[e];
    int c = ei[NEDGE + e];
    int pos = atomicAdd(&cursor[c], 1);
    csr_src[pos] = r;
    csr_nrm[pos] = dinv[r] * dinv[c];
}

// wenc [500,4096] fp32 -> [512,4096] bf16, pad rows zero
__global__ void cast_wenc_k(const float* __restrict__ w, unsigned short* __restrict__ wb) {
    int i = blockIdx.x * 256 + threadIdx.x;
    int row = i >> 12;
    wb[i] = (row < EMB) ? f2bf(w[i]) : (unsigned short)0;
}

// wdec [4096,500] fp32 -> [4096,512] bf16, pad cols zero
__global__ void cast_wdec_k(const float* __restrict__ w, unsigned short* __restrict__ wb) {
    int i = blockIdx.x * 256 + threadIdx.x;
    int row = i >> 9;
    int col = i & 511;
    wb[i] = (col < EMB) ? f2bf(w[row * EMB + col]) : (unsigned short)0;
}

// C[M,N] = act(A[M,K] @ B[N,K]^T + bias). BMx128 tile, BK=64, 4 waves.
// All staging is async global_load_lds (width 16), LINEAR LDS layouts.
// AF32: A is fp32 and stays fp32 in LDS; converted to bf16 at fragment-read
//       via packed v_cvt_pk_bf16_f32 (16 cvt per wave per K-step).
// BM=64 (encode) doubles the grid to 1024 blocks -> 4 blocks/CU with
// __launch_bounds__(256,4); BM=128 (decode) is the m97 tile.
// SIG: sigmoid + bf16 store (pad cols >= NL stored as 0); else fp32 store.
template<int BM, bool AF32, bool SIG>
__global__ __launch_bounds__(256, 4) void gemm_bt(
    const void* __restrict__ Av, const unsigned short* __restrict__ B,
    const float* __restrict__ bias, void* __restrict__ Cout,
    int M, int N, int K, int NL)
{
    constexpr int BN = 128, BK = 64;
    constexpr int MI = BM / 32;              // M-fragments per wave (64->2, 128->4)
    constexpr int ABYTES = AF32 ? 4 : 2;
    __shared__ __align__(16) char AsRaw[BM * BK * ABYTES];
    __shared__ __align__(16) char BsRaw[BN * BK * 2];

    int tid = threadIdx.x;
    int lane = tid & 63;
    int wave = tid >> 6;
    int rowA0 = blockIdx.x * BM;
    int colB0 = blockIdx.y * BN;
    int wm = (wave >> 1) * (BM / 2);
    int wn = (wave & 1) * 64;

    f32x4_t acc[MI][4];
    #pragma unroll
    for (int i = 0; i < MI; ++i)
        #pragma unroll
        for (int j = 0; j < 4; ++j)
            acc[i][j] = (f32x4_t){0.f, 0.f, 0.f, 0.f};

    int fr = lane & 15;
    int kb = (lane >> 4) * 8;                // bf16-elem offset within a 32-k slice

    for (int k0 = 0; k0 < K; k0 += BK) {
        __syncthreads();
        if constexpr (AF32) {
            // A: [BM=64][BK=64] fp32, 16 KB. One instr = 1024B = 4 rows.
            const float* A = (const float*)Av;
            float* AsF = (float*)AsRaw;
            int r = wave * 16 + (lane >> 4);
            int c = (lane & 15) * 4;
            #pragma unroll
            for (int t = 0; t < 4; ++t)
                gload_lds16(A + (size_t)(rowA0 + r + t * 4) * K + k0 + c,
                            AsF + (wave * 16 + t * 4) * BK);
        } else {
            // A: [BM=128][BK=64] bf16, 16 KB. One instr = 1024B = 8 rows.
            const unsigned short* A = (const unsigned short*)Av;
            unsigned short* AsU = (unsigned short*)AsRaw;
            int r = wave * 32 + (lane >> 3);
            int c = (lane & 7) * 8;
            #pragma unroll
            for (int t = 0; t < 4; ++t)
                gload_lds16(A + (size_t)(rowA0 + r + t * 8) * K + k0 + c,
                            AsU + (wave * 32 + t * 8) * BK);
        }
        {
            // B: [128][64] bf16, 16 KB.
            unsigned short* BsU = (unsigned short*)BsRaw;
            int r = wave * 32 + (lane >> 3);
            int c = (lane & 7) * 8;
            #pragma unroll
            for (int t = 0; t < 4; ++t)
                gload_lds16(B + (size_t)(colB0 + r + t * 8) * K + k0 + c,
                            BsU + (wave * 32 + t * 8) * BK);
        }
        __syncthreads();

        #pragma unroll
        for (int ks = 0; ks < 2; ++ks) {
            bf16x8_t af[MI], bfr[4];
            if constexpr (AF32) {
                const float* AsF = (const float*)AsRaw;
                #pragma unroll
                for (int i = 0; i < MI; ++i)
                    af[i] = cvt8(AsF + (wm + i * 16 + fr) * BK + ks * 32 + kb);
            } else {
                const unsigned short* AsU = (const unsigned short*)AsRaw;
                #pragma unroll
                for (int i = 0; i < MI; ++i)
                    af[i] = *(const bf16x8_t*)&AsU[(wm + i * 16 + fr) * BK + ks * 32 + kb];
            }
            const unsigned short* BsU = (const unsigned short*)BsRaw;
            #pragma unroll
            for (int j = 0; j < 4; ++j)
                bfr[j] = *(const bf16x8_t*)&BsU[(wn + j * 16 + fr) * BK + ks * 32 + kb];
            #pragma unroll
            for (int i = 0; i < MI; ++i)
                #pragma unroll
                for (int j = 0; j < 4; ++j)
                    acc[i][j] = __builtin_amdgcn_mfma_f32_16x16x32_bf16(af[i], bfr[j], acc[i][j], 0, 0, 0);
        }
    }

    // C/D layout: col = lane&15, row = (lane>>4)*4 + reg
    int cl = lane & 15;
    int rq = (lane >> 4) * 4;
    #pragma unroll
    for (int j = 0; j < 4; ++j) {
        int col = colB0 + wn + j * 16 + cl;
        float b = (col < NL) ? bias[col] : 0.f;
        #pragma unroll
        for (int i = 0; i < MI; ++i) {
            #pragma unroll
            for (int rr = 0; rr < 4; ++rr) {
                int row = rowA0 + wm + i * 16 + rq + rr;
                float v = acc[i][j][rr] + b;
                if constexpr (SIG) {
                    v = 1.f / (1.f + __expf(-v));
                    unsigned short o = (col < NL) ? f2bf(v) : (unsigned short)0;
                    ((unsigned short*)Cout)[(size_t)row * N + col] = o;
                } else {
                    ((float*)Cout)[(size_t)row * N + col] = v;
                }
            }
        }
    }
}

// one wave per target node: h2[n] = sum_{e: col==n} norm_e * cw * h[src_e] + h[n]
__global__ __launch_bounds__(256) void aggregate_k(
    const unsigned short* __restrict__ h, const int* __restrict__ colptr,
    const int* __restrict__ csr_src, const float* __restrict__ csr_nrm,
    const float* __restrict__ convw, unsigned short* __restrict__ h2)
{
    int lane = threadIdx.x & 63;
    int node = blockIdx.x * 4 + (threadIdx.x >> 6);
    float cw = convw[0];
    float acc[8] = {0.f, 0.f, 0.f, 0.f, 0.f, 0.f, 0.f, 0.f};
    int p0 = colptr[node], p1 = colptr[node + 1];
    int off = lane * 8;
    for (int i = p0; i < p1; ++i) {
        int r = csr_src[i];
        float w = csr_nrm[i] * cw;
        uint4 hv = *(const uint4*)(h + (size_t)r * EMBP + off);
        const unsigned short* hs = (const unsigned short*)&hv;
        #pragma unroll
        for (int j = 0; j < 8; ++j) acc[j] += w * bf2f(hs[j]);
    }
    uint4 hn = *(const uint4*)(h + (size_t)node * EMBP + off);
    const unsigned short* hs = (const unsigned short*)&hn;
    uint4 o;
    unsigned short ov[8];
    #pragma unroll
    for (int j = 0; j < 8; ++j) ov[j] = f2bf(acc[j] + bf2f(hs[j]));
    o.x = (unsigned)ov[0] | ((unsigned)ov[1] << 16);
    o.y = (unsigned)ov[2] | ((unsigned)ov[3] << 16);
    o.z = (unsigned)ov[4] | ((unsigned)ov[5] << 16);
    o.w = (unsigned)ov[6] | ((unsigned)ov[7] << 16);
    *(uint4*)(h2 + (size_t)node * EMBP + off) = o;
}

extern "C" void kernel_launch(void* const* d_in, const int* in_sizes, int n_in,
                              void* d_out, int out_size, void* d_ws, size_t ws_size,
                              hipStream_t stream) {
    const float* x = (const float*)d_in[0];
    const int* ei = (const int*)d_in[1];     // int32 [2,E] (harness converts integer inputs)
    const float* wenc = (const float*)d_in[2];
    const float* benc = (const float*)d_in[3];
    const float* wdec = (const float*)d_in[4];
    const float* bdec = (const float*)d_in[5];
    const float* convw = (const float*)d_in[6];
    float* out = (float*)d_out;

    char* ws = (char*)d_ws;
    size_t off = 0;
    auto alloc = [&](size_t bytes) -> void* {
        void* p = ws + off;
        off += (bytes + 255) & ~(size_t)255;
        return p;
    };
    unsigned short* wencb = (unsigned short*)alloc((size_t)EMBP * IN_SIZE * 2);
    unsigned short* wdecb = (unsigned short*)alloc((size_t)IN_SIZE * EMBP * 2);
    unsigned short* h     = (unsigned short*)alloc((size_t)N_NODES * EMBP * 2);
    unsigned short* h2    = (unsigned short*)alloc((size_t)N_NODES * EMBP * 2);
    int*   deg     = (int*)alloc(N_NODES * 4);    // deg & coldeg contiguous (zeroed together)
    int*   coldeg  = (int*)alloc(N_NODES * 4);
    float* dinv    = (float*)alloc(N_NODES * 4);
    int*   colptr  = (int*)alloc((N_NODES + 1) * 4);
    int*   cursor  = (int*)alloc(N_NODES * 4);
    int*   csr_src = (int*)alloc((size_t)NEDGE * 4);
    float* csr_nrm = (float*)alloc((size_t)NEDGE * 4);

    zero_i32<<<(2 * N_NODES) / 256, 256, 0, stream>>>(deg, 2 * N_NODES);
    hist_k<<<NEDGE / 256, 256, 0, stream>>>(ei, deg, coldeg);
    dinv_k<<<N_NODES / 256, 256, 0, stream>>>(deg, dinv);
    scan_k<<<1, 256, 0, stream>>>(coldeg, colptr, cursor);
    fill_k<<<NEDGE / 256, 256, 0, stream>>>(ei, dinv, cursor, csr_src, csr_nrm);
    cast_wenc_k<<<(EMBP * IN_SIZE) / 256, 256, 0, stream>>>(wenc, wencb);
    cast_wdec_k<<<(IN_SIZE * EMBP) / 256, 256, 0, stream>>>(wdec, wdecb);

    // encode: h = sigmoid(x @ wenc^T + benc)  [16384, 512(bf16, cols>=500 zeroed)]
    // BM=64 tile -> 1024 blocks -> 4 blocks/CU
    gemm_bt<64, true, true><<<dim3(N_NODES / 64, EMBP / 128), 256, 0, stream>>>(
        x, wencb, benc, h, N_NODES, EMBP, IN_SIZE, EMB);
    // GCN propagate + residual
    aggregate_k<<<N_NODES / 4, 256, 0, stream>>>(h, colptr, csr_src, csr_nrm, convw, h2);
    // decode: out = h2 @ wdec^T + bdec  [16384, 4096] fp32
    gemm_bt<128, false, false><<<dim3(N_NODES / 128, IN_SIZE / 128), 256, 0, stream>>>(
        h2, wdecb, bdec, out, N_NODES, IN_SIZE, EMBP, IN_SIZE);
}

// Round 3
// 838.881 us; speedup vs baseline: 1.0125x; 1.0125x over previous
//
#include <hip/hip_runtime.h>
#include <hip/hip_bf16.h>
#include <stdint.h>

#define N_NODES 16384
#define IN_SIZE 4096
#define EMB 500
#define EMBP 512
#define NEDGE 524288

typedef __attribute__((ext_vector_type(8))) short bf16x8_t;
typedef __attribute__((ext_vector_type(4))) float f32x4_t;

__device__ __forceinline__ unsigned short f2bf(float f) {
    union { float f; unsigned u; } v; v.f = f;
    unsigned r = v.u + 0x7FFFu + ((v.u >> 16) & 1u);
    return (unsigned short)(r >> 16);
}
__device__ __forceinline__ float bf2f(unsigned short h) {
    union { float f; unsigned u; } v; v.u = ((unsigned)h) << 16;
    return v.f;
}

// packed fp32x2 -> bf16x2 (RNE); lowers to v_cvt_pk_bf16_f32 on gfx950
__device__ __forceinline__ unsigned pkbf2(float a, float b) {
    union { __hip_bfloat162 h; unsigned u; } c;
    c.h = __float22bfloat162_rn(float2{a, b});
    return c.u;
}

// async global->LDS, 16B per lane. LDS dest is wave-uniform base + lane*16.
__device__ __forceinline__ void gload_lds16(const void* g, void* l) {
    __builtin_amdgcn_global_load_lds(
        (__attribute__((address_space(1))) void*)(g),
        (__attribute__((address_space(3))) void*)(l),
        16, 0, 0);
}

__global__ void zero_i32(int* p, int n) {
    int i = blockIdx.x * 256 + threadIdx.x;
    if (i < n) p[i] = 0;
}

// edge_index delivered by harness as int32 [2, E]: row = ei[e], col = ei[E + e]
__global__ void hist_k(const int* __restrict__ ei, int* __restrict__ deg, int* __restrict__ coldeg) {
    int e = blockIdx.x * 256 + threadIdx.x;
    int r = ei[e];
    int c = ei[NEDGE + e];
    atomicAdd(&deg[r], 1);
    atomicAdd(&coldeg[c], 1);
}

__global__ void dinv_k(const int* __restrict__ deg, float* __restrict__ dinv) {
    int i = blockIdx.x * 256 + threadIdx.x;
    int d = deg[i];
    dinv[i] = d > 0 ? rsqrtf((float)d) : 0.f;
}

// exclusive scan of coldeg[16384] -> colptr[16385]; cursor = copy of colptr[0:16384]
__global__ void scan_k(const int* __restrict__ coldeg, int* __restrict__ colptr, int* __restrict__ cursor) {
    __shared__ int part[256];
    int t = threadIdx.x;
    int base = t * 64;
    int s = 0;
    for (int i = 0; i < 64; ++i) s += coldeg[base + i];
    part[t] = s;
    __syncthreads();
    for (int off = 1; off < 256; off <<= 1) {
        int v = part[t];
        int add = (t >= off) ? part[t - off] : 0;
        __syncthreads();
        part[t] = v + add;
        __syncthreads();
    }
    int ex = (t > 0) ? part[t - 1] : 0;
    for (int i = 0; i < 64; ++i) {
        colptr[base + i] = ex;
        cursor[base + i] = ex;
        ex += coldeg[base + i];
    }
    if (t == 255) colptr[N_NODES] = ex;
}

__global__ void fill_k(const int* __restrict__ ei, const float* __restrict__ dinv,
                       int* __restrict__ cursor, int* __restrict__ csr_src, float* __restrict__ csr_nrm) {
    int e = blockIdx.x * 256 + threadIdx.x;
    int r = ei[e];
    int c = ei[NEDGE + e];
    int pos = atomicAdd(&cursor[c], 1);
    csr_src[pos] = r;
    csr_nrm[pos] = dinv[r] * dinv[c];
}

// wenc [500,4096] fp32 -> [512,4096] bf16, pad rows zero
__global__ void cast_wenc_k(const float* __restrict__ w, unsigned short* __restrict__ wb) {
    int i = blockIdx.x * 256 + threadIdx.x;
    int row = i >> 12;
    wb[i] = (row < EMB) ? f2bf(w[i]) : (unsigned short)0;
}

// wdec [4096,500] fp32 -> [4096,512] bf16, pad cols zero
__global__ void cast_wdec_k(const float* __restrict__ w, unsigned short* __restrict__ wb) {
    int i = blockIdx.x * 256 + threadIdx.x;
    int row = i >> 9;
    int col = i & 511;
    wb[i] = (col < EMB) ? f2bf(w[row * EMB + col]) : (unsigned short)0;
}

// C[M,N] = act(A[M,K] @ B[N,K]^T + bias). 128x128 tile, BK=32 (m97 geometry).
// All staging is async global_load_lds (width 16).
// Bank-conflict fix under the linear-LDS-dest constraint (rule #21): the
// GLOBAL source address is permuted per-lane so the LDS tile is XOR-swizzled,
// and fragment reads apply the same XOR. bf16 rows (64B): 16B-chunk ^= (row>>1)&3
// -> 4 slots x 2 bank-phases = 8 groups -> 2-way (free, m136). fp32 rows (128B):
// 16B-chunk ^= row&7 -> 8 slots -> 2-way (free). Round 2's 16-way conflict
// (8.4e7 cycles) came from BK=64 linear; this removes it at zero instr cost.
// AF32: A is fp32, stays fp32 in LDS, converted at fragment-read via
// v_cvt_pk_bf16_f32 (16/wave/iter) — staging itself is pure async DMA.
// SIG: sigmoid + bf16 store (pad cols >= NL stored as 0); else fp32 store.
template<bool AF32, bool SIG>
__global__ __launch_bounds__(256, 4) void gemm_bt(
    const void* __restrict__ Av, const unsigned short* __restrict__ B,
    const float* __restrict__ bias, void* __restrict__ Cout,
    int M, int N, int K, int NL)
{
    constexpr int BM = 128, BN = 128, BK = 32;
    constexpr int ABYTES = AF32 ? 4 : 2;
    __shared__ __align__(16) char AsRaw[BM * BK * ABYTES];   // 16 KB (fp32) / 8 KB (bf16)
    __shared__ __align__(16) unsigned short Bs[BN * BK];     // 8 KB

    int tid = threadIdx.x;
    int lane = tid & 63;
    int wave = tid >> 6;
    int rowA0 = blockIdx.x * BM;
    int colB0 = blockIdx.y * BN;
    int wm = (wave >> 1) * 64;
    int wn = (wave & 1) * 64;

    f32x4_t acc[4][4];
    #pragma unroll
    for (int i = 0; i < 4; ++i)
        #pragma unroll
        for (int j = 0; j < 4; ++j)
            acc[i][j] = (f32x4_t){0.f, 0.f, 0.f, 0.f};

    int fr = lane & 15;          // fragment row within 16
    int g  = lane >> 4;          // k-quarter (16B bf16 chunk index)

    // bf16 staging: 16 rows/instr, 4 lanes/row, 16B chunk c4; source chunk swizzled
    int r16 = lane >> 2;
    int c4  = lane & 3;
    int sColB = (c4 ^ ((r16 >> 1) & 3)) * 8;     // bf16 elems
    // fp32 staging: 8 rows/instr, 8 lanes/row
    int r8  = lane >> 3;
    int c8  = lane & 7;
    int sColA32 = (c8 ^ (r8 & 7)) * 4;           // fp32 elems

    for (int k0 = 0; k0 < K; k0 += BK) {
        __syncthreads();
        if constexpr (AF32) {
            const float* A = (const float*)Av;
            float* AsF = (float*)AsRaw;
            #pragma unroll
            for (int t = 0; t < 4; ++t)
                gload_lds16(A + (size_t)(rowA0 + wave * 32 + t * 8 + r8) * K + k0 + sColA32,
                            AsF + (wave * 32 + t * 8) * BK);
        } else {
            const unsigned short* A = (const unsigned short*)Av;
            unsigned short* AsU = (unsigned short*)AsRaw;
            #pragma unroll
            for (int t = 0; t < 2; ++t)
                gload_lds16(A + (size_t)(rowA0 + wave * 32 + t * 16 + r16) * K + k0 + sColB,
                            AsU + (wave * 32 + t * 16) * BK);
        }
        #pragma unroll
        for (int t = 0; t < 2; ++t)
            gload_lds16(B + (size_t)(colB0 + wave * 32 + t * 16 + r16) * K + k0 + sColB,
                        Bs + (wave * 32 + t * 16) * BK);
        __syncthreads();

        bf16x8_t af[4], bfr[4];
        #pragma unroll
        for (int i = 0; i < 4; ++i) {
            int row = wm + i * 16 + fr;
            if constexpr (AF32) {
                const float* AsF = (const float*)AsRaw;
                f32x4_t lo = *(const f32x4_t*)&AsF[row * BK + (((2 * g)     ^ (fr & 7)) * 4)];
                f32x4_t hi = *(const f32x4_t*)&AsF[row * BK + (((2 * g + 1) ^ (fr & 7)) * 4)];
                union { bf16x8_t v; unsigned u[4]; } rr;
                rr.u[0] = pkbf2(lo[0], lo[1]);
                rr.u[1] = pkbf2(lo[2], lo[3]);
                rr.u[2] = pkbf2(hi[0], hi[1]);
                rr.u[3] = pkbf2(hi[2], hi[3]);
                af[i] = rr.v;
            } else {
                const unsigned short* AsU = (const unsigned short*)AsRaw;
                af[i] = *(const bf16x8_t*)&AsU[row * BK + ((g ^ ((fr >> 1) & 3)) * 8)];
            }
        }
        #pragma unroll
        for (int j = 0; j < 4; ++j) {
            int row = wn + j * 16 + fr;
            bfr[j] = *(const bf16x8_t*)&Bs[row * BK + ((g ^ ((fr >> 1) & 3)) * 8)];
        }
        #pragma unroll
        for (int i = 0; i < 4; ++i)
            #pragma unroll
            for (int j = 0; j < 4; ++j)
                acc[i][j] = __builtin_amdgcn_mfma_f32_16x16x32_bf16(af[i], bfr[j], acc[i][j], 0, 0, 0);
    }

    // C/D layout: col = lane&15, row = (lane>>4)*4 + reg
    int cl = lane & 15;
    int rq = (lane >> 4) * 4;
    #pragma unroll
    for (int j = 0; j < 4; ++j) {
        int col = colB0 + wn + j * 16 + cl;
        float b = (col < NL) ? bias[col] : 0.f;
        #pragma unroll
        for (int i = 0; i < 4; ++i) {
            #pragma unroll
            for (int rr = 0; rr < 4; ++rr) {
                int row = rowA0 + wm + i * 16 + rq + rr;
                float v = acc[i][j][rr] + b;
                if constexpr (SIG) {
                    v = 1.f / (1.f + __expf(-v));
                    unsigned short o = (col < NL) ? f2bf(v) : (unsigned short)0;
                    ((unsigned short*)Cout)[(size_t)row * N + col] = o;
                } else {
                    ((float*)Cout)[(size_t)row * N + col] = v;
                }
            }
        }
    }
}

// one wave per target node: h2[n] = sum_{e: col==n} norm_e * cw * h[src_e] + h[n]
// 2-edge unroll doubles memory-level parallelism in the gather loop.
__global__ __launch_bounds__(256) void aggregate_k(
    const unsigned short* __restrict__ h, const int* __restrict__ colptr,
    const int* __restrict__ csr_src, const float* __restrict__ csr_nrm,
    const float* __restrict__ convw, unsigned short* __restrict__ h2)
{
    int lane = threadIdx.x & 63;
    int node = blockIdx.x * 4 + (threadIdx.x >> 6);
    float cw = convw[0];
    float acc[8] = {0.f, 0.f, 0.f, 0.f, 0.f, 0.f, 0.f, 0.f};
    int p0 = colptr[node], p1 = colptr[node + 1];
    int off = lane * 8;
    int i = p0;
    for (; i + 1 < p1; i += 2) {
        int r0 = csr_src[i], r1 = csr_src[i + 1];
        float w0 = csr_nrm[i] * cw, w1 = csr_nrm[i + 1] * cw;
        uint4 v0 = *(const uint4*)(h + (size_t)r0 * EMBP + off);
        uint4 v1 = *(const uint4*)(h + (size_t)r1 * EMBP + off);
        const unsigned short* s0 = (const unsigned short*)&v0;
        const unsigned short* s1 = (const unsigned short*)&v1;
        #pragma unroll
        for (int j = 0; j < 8; ++j) acc[j] += w0 * bf2f(s0[j]) + w1 * bf2f(s1[j]);
    }
    if (i < p1) {
        int r = csr_src[i];
        float w = csr_nrm[i] * cw;
        uint4 hv = *(const uint4*)(h + (size_t)r * EMBP + off);
        const unsigned short* hs = (const unsigned short*)&hv;
        #pragma unroll
        for (int j = 0; j < 8; ++j) acc[j] += w * bf2f(hs[j]);
    }
    uint4 hn = *(const uint4*)(h + (size_t)node * EMBP + off);
    const unsigned short* hs = (const unsigned short*)&hn;
    uint4 o;
    unsigned short ov[8];
    #pragma unroll
    for (int j = 0; j < 8; ++j) ov[j] = f2bf(acc[j] + bf2f(hs[j]));
    o.x = (unsigned)ov[0] | ((unsigned)ov[1] << 16);
    o.y = (unsigned)ov[2] | ((unsigned)ov[3] << 16);
    o.z = (unsigned)ov[4] | ((unsigned)ov[5] << 16);
    o.w = (unsigned)ov[6] | ((unsigned)ov[7] << 16);
    *(uint4*)(h2 + (size_t)node * EMBP + off) = o;
}

extern "C" void kernel_launch(void* const* d_in, const int* in_sizes, int n_in,
                              void* d_out, int out_size, void* d_ws, size_t ws_size,
                              hipStream_t stream) {
    const float* x = (const float*)d_in[0];
    const int* ei = (const int*)d_in[1];     // int32 [2,E] (harness converts integer inputs)
    const float* wenc = (const float*)d_in[2];
    const float* benc = (const float*)d_in[3];
    const float* wdec = (const float*)d_in[4];
    const float* bdec = (const float*)d_in[5];
    const float* convw = (const float*)d_in[6];
    float* out = (float*)d_out;

    char* ws = (char*)d_ws;
    size_t off = 0;
    auto alloc = [&](size_t bytes) -> void* {
        void* p = ws + off;
        off += (bytes + 255) & ~(size_t)255;
        return p;
    };
    unsigned short* wencb = (unsigned short*)alloc((size_t)EMBP * IN_SIZE * 2);
    unsigned short* wdecb = (unsigned short*)alloc((size_t)IN_SIZE * EMBP * 2);
    unsigned short* h     = (unsigned short*)alloc((size_t)N_NODES * EMBP * 2);
    unsigned short* h2    = (unsigned short*)alloc((size_t)N_NODES * EMBP * 2);
    int*   deg     = (int*)alloc(N_NODES * 4);    // deg & coldeg contiguous (zeroed together)
    int*   coldeg  = (int*)alloc(N_NODES * 4);
    float* dinv    = (float*)alloc(N_NODES * 4);
    int*   colptr  = (int*)alloc((N_NODES + 1) * 4);
    int*   cursor  = (int*)alloc(N_NODES * 4);
    int*   csr_src = (int*)alloc((size_t)NEDGE * 4);
    float* csr_nrm = (float*)alloc((size_t)NEDGE * 4);

    zero_i32<<<(2 * N_NODES) / 256, 256, 0, stream>>>(deg, 2 * N_NODES);
    hist_k<<<NEDGE / 256, 256, 0, stream>>>(ei, deg, coldeg);
    dinv_k<<<N_NODES / 256, 256, 0, stream>>>(deg, dinv);
    scan_k<<<1, 256, 0, stream>>>(coldeg, colptr, cursor);
    fill_k<<<NEDGE / 256, 256, 0, stream>>>(ei, dinv, cursor, csr_src, csr_nrm);
    cast_wenc_k<<<(EMBP * IN_SIZE) / 256, 256, 0, stream>>>(wenc, wencb);
    cast_wdec_k<<<(IN_SIZE * EMBP) / 256, 256, 0, stream>>>(wdec, wdecb);

    // encode: h = sigmoid(x @ wenc^T + benc)  [16384, 512(bf16, cols>=500 zeroed)]
    gemm_bt<true, true><<<dim3(N_NODES / 128, EMBP / 128), 256, 0, stream>>>(
        x, wencb, benc, h, N_NODES, EMBP, IN_SIZE, EMB);
    // GCN propagate + residual
    aggregate_k<<<N_NODES / 4, 256, 0, stream>>>(h, colptr, csr_src, csr_nrm, convw, h2);
    // decode: out = h2 @ wdec^T + bdec  [16384, 4096] fp32
    gemm_bt<false, false><<<dim3(N_NODES / 128, IN_SIZE / 128), 256, 0, stream>>>(
        h2, wdecb, bdec, out, N_NODES, IN_SIZE, EMBP, IN_SIZE);
}